// Round 16
// baseline (158.816 us; speedup 1.0000x reference)
//
#include <hip/hip_runtime.h>

// ---------------------------------------------------------------------------
// HeteroGNN, round 16: persistent-B final GEMM (128KB B staged once per
// 1024-thread block, 512 rows/block, 1 barrier, 16 waves/CU).
//   x_image/x_text stored fp8-e4m3 (HW cvt); means bf16; GEMM bf16 MFMA.
//   out = relu( [mean_i | mean_t | x_user] @ [Wl_i; Wl_t; W_user@(Wr_i+Wr_t)]
//               + (b_user@(Wr_i+Wr_t) + bl_i + bl_t) )        [MFMA, K=512]
// CSR: two-level bucket partition, zero global atomics (r9/r14).
// gather: 8 lanes/node, 16B(=16 fp8)/lane, unroll-4 (r15).
// MFMA 16x16x32_bf16: A row=lane&15, k=(lane>>4)*8+j; B col=lane&15;
// D col=lane&15, row=(lane>>4)*4+reg  [m89-verified].
// ---------------------------------------------------------------------------

#define BK 4096          // edges per level-1 block
#define MAXBUK 256       // >= nbuk = ceil(2N/1024) = 196

typedef __attribute__((ext_vector_type(8))) short bf16x8;
typedef __attribute__((ext_vector_type(8))) unsigned short u16x8;
typedef __attribute__((ext_vector_type(4))) float f32x4;
typedef __attribute__((ext_vector_type(2))) float f32x2;

__device__ __forceinline__ ushort f2b(float x) {
    union { float f; unsigned u; } v; v.f = x;
    unsigned r = (v.u + 0x7FFF + ((v.u >> 16) & 1)) >> 16;   // RNE
    return (ushort)r;
}
__device__ __forceinline__ float b2f(ushort u) {
    union { unsigned u; float f; } v; v.u = (unsigned)u << 16;
    return v.f;
}
// decode 4 fp8 (one u32) and accumulate into a[0..3]
__device__ __forceinline__ void acc4(unsigned w, float* a) {
    f32x2 lo = __builtin_amdgcn_cvt_pk_f32_fp8((int)w, false);
    f32x2 hi = __builtin_amdgcn_cvt_pk_f32_fp8((int)w, true);
    a[0] += lo[0]; a[1] += lo[1]; a[2] += hi[0]; a[3] += hi[1];
}

// ---- fused front: [pack | bucket hist (LDS) | fp8 convert] by block range ----
__global__ __launch_bounds__(256) void k_front(
        const float* __restrict__ x_image, const float* __restrict__ x_text,
        const int* __restrict__ edge_i, const int* __restrict__ edge_t,
        const float* __restrict__ Wl_i, const float* __restrict__ Wl_t,
        const float* __restrict__ W_user, const float* __restrict__ b_user,
        const float* __restrict__ Wr_i, const float* __restrict__ Wr_t,
        const float* __restrict__ bl_i, const float* __restrict__ bl_t,
        unsigned char* __restrict__ xib, unsigned char* __restrict__ xtb,
        ushort* __restrict__ Bp, float* __restrict__ bias,
        int* __restrict__ counts,
        int N, int E, int nblkR, int nbuk, int nbP) {
    __shared__ int h[MAXBUK];
    const int bid = blockIdx.x;
    const int tid = threadIdx.x;
    const int NBLK = 2 * nblkR;

    if (bid < nbP) {
        // ---- pack Bp [512x128] = [Wl_i; Wl_t; W_user@(Wr_i+Wr_t)] + bias ----
        int i = bid * 256 + tid;                     // < 65536
        int j = i & 7, lane = (i >> 3) & 63, cf = (i >> 9) & 7, ks = i >> 12;
        int kk = ks * 32 + (lane >> 4) * 8 + j;
        int col = cf * 16 + (lane & 15);
        float v;
        if (kk < 128)      v = Wl_i[kk * 128 + col];
        else if (kk < 256) v = Wl_t[(kk - 128) * 128 + col];
        else {
            int k2 = kk - 256;
            float s = 0.f;
            for (int c1 = 0; c1 < 128; ++c1)
                s += W_user[k2 * 128 + c1] * (Wr_i[c1 * 128 + col] + Wr_t[c1 * 128 + col]);
            v = s;
        }
        Bp[i] = f2b(v);
        if (i < 128) {
            float b = bl_i[i] + bl_t[i];
            for (int k2 = 0; k2 < 128; ++k2)
                b += b_user[k2] * (Wr_i[k2 * 128 + i] + Wr_t[k2 * 128 + i]);
            bias[i] = b;
        }
    } else if (bid < nbP + NBLK) {
        // ---- level-1 histogram of bucket = key>>10, LDS atomics only ----
        int hb = bid - nbP;
        int rel = (hb >= nblkR) ? 1 : 0;
        int blk = hb - rel * nblkR;
        const int* eg = rel ? edge_t : edge_i;
        const int relN = rel * N;
        for (int i = tid; i < nbuk; i += 256) h[i] = 0;
        __syncthreads();
        int base = blk * BK;
        #pragma unroll
        for (int j = 0; j < 4; ++j) {
            int e = base + (j * 256 + tid) * 4;
            if (e + 3 < E) {
                int4 d4 = *reinterpret_cast<const int4*>(eg + E + e);
                atomicAdd(&h[(relN + d4.x) >> 10], 1);
                atomicAdd(&h[(relN + d4.y) >> 10], 1);
                atomicAdd(&h[(relN + d4.z) >> 10], 1);
                atomicAdd(&h[(relN + d4.w) >> 10], 1);
            } else {
                for (int q = 0; q < 4; ++q) {
                    int ee = e + q;
                    if (ee < E) atomicAdd(&h[(relN + eg[E + ee]) >> 10], 1);
                }
            }
        }
        __syncthreads();
        for (int i = tid; i < nbuk; i += 256) counts[(size_t)hb * nbuk + i] = h[i];
    } else {
        // ---- x_image/x_text f32 -> fp8 e4m3 (HW cvt, RNE) ----
        int t = (bid - nbP - NBLK) * 256 + tid;
        int n8 = N * 16;
        if (t >= 2 * n8) return;
        int relc = (t >= n8) ? 1 : 0;
        const float* src = relc ? x_text : x_image;
        unsigned char* dst = relc ? xtb : xib;
        int i = relc ? t - n8 : t;
        float4 f0 = *reinterpret_cast<const float4*>(src + (size_t)i * 8);
        float4 f1 = *reinterpret_cast<const float4*>(src + (size_t)i * 8 + 4);
        int w0 = 0, w1 = 0;
        w0 = __builtin_amdgcn_cvt_pk_fp8_f32(f0.x, f0.y, w0, false);
        w0 = __builtin_amdgcn_cvt_pk_fp8_f32(f0.z, f0.w, w0, true);
        w1 = __builtin_amdgcn_cvt_pk_fp8_f32(f1.x, f1.y, w1, false);
        w1 = __builtin_amdgcn_cvt_pk_fp8_f32(f1.z, f1.w, w1, true);
        *reinterpret_cast<uint2*>(dst + (size_t)i * 8) = make_uint2((unsigned)w0, (unsigned)w1);
    }
}

// ---- s1: per-bucket exclusive prefix over blocks (in-place) + totals ----
__global__ __launch_bounds__(256) void k_s1(int* __restrict__ counts,
                                            int* __restrict__ T,
                                            int NBLK, int nbuk) {
    __shared__ int a[512];
    __shared__ int ps[256];
    const int b = blockIdx.x, t = threadIdx.x;
    a[t]       = (t < NBLK)       ? counts[(size_t)t * nbuk + b] : 0;
    a[t + 256] = (t + 256 < NBLK) ? counts[(size_t)(t + 256) * nbuk + b] : 0;
    __syncthreads();
    int x0 = a[2 * t], x1 = a[2 * t + 1];
    int s = x0 + x1;
    ps[t] = s; __syncthreads();
    for (int off = 1; off < 256; off <<= 1) {
        int add = (t >= off) ? ps[t - off] : 0;
        __syncthreads();
        ps[t] += add;
        __syncthreads();
    }
    int ex = ps[t] - s;
    if (2 * t < NBLK)     counts[(size_t)(2 * t) * nbuk + b] = ex;
    if (2 * t + 1 < NBLK) counts[(size_t)(2 * t + 1) * nbuk + b] = ex + x0;
    if (t == 255) T[b] = ps[255];
}

// ---- s2: exclusive scan of bucket totals -> bucket bases ----
__global__ __launch_bounds__(256) void k_s2(const int* __restrict__ T,
                                            int* __restrict__ Bb,
                                            int* __restrict__ rowptr,
                                            int M, int Etot, int nbuk) {
    __shared__ int sh[256];
    int t = threadIdx.x;
    int v = (t < nbuk) ? T[t] : 0;
    sh[t] = v; __syncthreads();
    for (int off = 1; off < 256; off <<= 1) {
        int add = (t >= off) ? sh[t - off] : 0;
        __syncthreads();
        sh[t] += add;
        __syncthreads();
    }
    if (t < nbuk) Bb[t] = sh[t] - v;
    if (t == 0) { Bb[nbuk] = Etot; rowptr[M] = Etot; }
}

// ---- part1 (512 thr): scatter packed pairs into bucket regions ----
__global__ __launch_bounds__(512) void k_part1(
        const int* __restrict__ edge_i, const int* __restrict__ edge_t,
        const int* __restrict__ counts, const int* __restrict__ Bb,
        unsigned* __restrict__ pairs, int N, int E, int nblkR, int nbuk) {
    __shared__ int cur[MAXBUK];
    const int bid = blockIdx.x, tid = threadIdx.x;
    int rel = (bid >= nblkR) ? 1 : 0;
    int blk = bid - rel * nblkR;
    const int* eg = rel ? edge_t : edge_i;
    const int relN = rel * N;
    for (int i = tid; i < nbuk; i += 512)
        cur[i] = Bb[i] + counts[(size_t)bid * nbuk + i];
    __syncthreads();
    int base = blk * BK;
    #pragma unroll
    for (int j = 0; j < 2; ++j) {
        int e = base + (j * 512 + tid) * 4;
        if (e + 3 < E) {
            int4 d4 = *reinterpret_cast<const int4*>(eg + E + e);
            int4 s4 = *reinterpret_cast<const int4*>(eg + e);
            int k0 = relN + d4.x, k1 = relN + d4.y, k2 = relN + d4.z, k3 = relN + d4.w;
            int p0 = atomicAdd(&cur[k0 >> 10], 1);
            pairs[p0] = ((unsigned)(k0 & 1023) << 17) | (unsigned)s4.x;
            int p1 = atomicAdd(&cur[k1 >> 10], 1);
            pairs[p1] = ((unsigned)(k1 & 1023) << 17) | (unsigned)s4.y;
            int p2 = atomicAdd(&cur[k2 >> 10], 1);
            pairs[p2] = ((unsigned)(k2 & 1023) << 17) | (unsigned)s4.z;
            int p3 = atomicAdd(&cur[k3 >> 10], 1);
            pairs[p3] = ((unsigned)(k3 & 1023) << 17) | (unsigned)s4.w;
        } else {
            for (int q = 0; q < 4; ++q) {
                int ee = e + q;
                if (ee < E) {
                    int k0 = relN + eg[E + ee];
                    int p0 = atomicAdd(&cur[k0 >> 10], 1);
                    pairs[p0] = ((unsigned)(k0 & 1023) << 17) | (unsigned)eg[ee];
                }
            }
        }
    }
}

// ---- part2 (512 thr): per-bucket (1024 keys) hist/scan -> rowptr + col ----
__global__ __launch_bounds__(512) void k_part2(
        const unsigned* __restrict__ pairs, const int* __restrict__ Bb,
        int* __restrict__ rowptr, int* __restrict__ col, int M) {
    __shared__ int h[1024];
    __shared__ int ps[512];
    const int b = blockIdx.x, t = threadIdx.x;
    const int key0 = b << 10;
    const int beg = Bb[b], end = Bb[b + 1];
    h[t] = 0; h[t + 512] = 0;
    __syncthreads();
    for (int p = beg + t; p < end; p += 512)
        atomicAdd(&h[pairs[p] >> 17], 1);
    __syncthreads();
    int v0 = h[2 * t], v1 = h[2 * t + 1];
    int s = v0 + v1;
    ps[t] = s; __syncthreads();
    for (int off = 1; off < 512; off <<= 1) {
        int add = (t >= off) ? ps[t - off] : 0;
        __syncthreads();
        ps[t] += add;
        __syncthreads();
    }
    int run = ps[t] - s + beg;
    __syncthreads();
    int k = key0 + 2 * t;
    if (k < M) rowptr[k] = run;
    h[2 * t] = run; run += v0;
    if (k + 1 < M) rowptr[k + 1] = run;
    h[2 * t + 1] = run;
    __syncthreads();
    for (int p = beg + t; p < end; p += 512) {
        unsigned pr = pairs[p];
        int slot = atomicAdd(&h[pr >> 17], 1);
        col[slot] = (int)(pr & 0x1FFFFu);
    }
}

// ---- gather-mean: 8 lanes/node, 16B(16 fp8)/lane, unroll-4, bf16 means ----
__global__ __launch_bounds__(256) void k_gather_mean(
        const unsigned char* __restrict__ xib, const unsigned char* __restrict__ xtb,
        const int* __restrict__ rowptr, const int* __restrict__ col,
        ushort* __restrict__ mi, ushort* __restrict__ mt, int N) {
    int t = blockIdx.x * 256 + threadIdx.x;
    int node = t >> 3, lane = t & 7;
    if (node >= N) return;
    int rel = blockIdx.y;
    const unsigned char* xs = rel ? xtb : xib;
    ushort* mean = rel ? mt : mi;
    const int c0 = lane * 16;            // element (= byte) offset in 128-elem row
    int rb = rel * N + node;
    int beg = rowptr[rb], end = rowptr[rb + 1];
    float a[16];
    #pragma unroll
    for (int q = 0; q < 16; ++q) a[q] = 0.f;
    int j = beg;
    for (; j + 3 < end; j += 4) {
        int s0 = col[j], s1 = col[j + 1], s2 = col[j + 2], s3 = col[j + 3];
        uint4 v0 = *reinterpret_cast<const uint4*>(xs + (size_t)s0 * 128 + c0);
        uint4 v1 = *reinterpret_cast<const uint4*>(xs + (size_t)s1 * 128 + c0);
        uint4 v2 = *reinterpret_cast<const uint4*>(xs + (size_t)s2 * 128 + c0);
        uint4 v3 = *reinterpret_cast<const uint4*>(xs + (size_t)s3 * 128 + c0);
        acc4(v0.x, a + 0); acc4(v0.y, a + 4); acc4(v0.z, a + 8); acc4(v0.w, a + 12);
        acc4(v1.x, a + 0); acc4(v1.y, a + 4); acc4(v1.z, a + 8); acc4(v1.w, a + 12);
        acc4(v2.x, a + 0); acc4(v2.y, a + 4); acc4(v2.z, a + 8); acc4(v2.w, a + 12);
        acc4(v3.x, a + 0); acc4(v3.y, a + 4); acc4(v3.z, a + 8); acc4(v3.w, a + 12);
    }
    for (; j < end; ++j) {
        uint4 v0 = *reinterpret_cast<const uint4*>(xs + (size_t)col[j] * 128 + c0);
        acc4(v0.x, a + 0); acc4(v0.y, a + 4); acc4(v0.z, a + 8); acc4(v0.w, a + 12);
    }
    float r = (end > beg) ? 1.0f / (float)(end - beg) : 0.0f;
    u16x8 o0, o1;
    #pragma unroll
    for (int q = 0; q < 8; ++q) { o0[q] = f2b(a[q] * r); o1[q] = f2b(a[q + 8] * r); }
    *reinterpret_cast<u16x8*>(mean + (size_t)node * 128 + c0) = o0;
    *reinterpret_cast<u16x8*>(mean + (size_t)node * 128 + c0 + 8) = o1;
}

// ---- out = relu( [mi|mt|x_user](K=512) @ Bp + bias ) : MFMA, full B in LDS ----
// 1024 thr / 16 waves / 512 rows per block; B (128KB) staged ONCE, 1 barrier.
__global__ __launch_bounds__(1024) void k_final_mfma(
        const ushort* __restrict__ mi, const ushort* __restrict__ mt,
        const float* __restrict__ x_user, const ushort* __restrict__ Bp,
        const float* __restrict__ bias, float* __restrict__ out, int N) {
    extern __shared__ u16x8 bl8[];               // 8192 entries = 128 KB
    const int tid = threadIdx.x;
    const int wid = tid >> 6, lane = tid & 63;
    const int r0g = blockIdx.x * 512 + wid * 32 + (lane & 15);
    const int rA0 = min(r0g, N - 1);
    const int rA1 = min(r0g + 16, N - 1);
    const int kh = (lane >> 4) * 8;
    f32x4 acc0[8] = {}, acc1[8] = {};

    const u16x8* Bp8 = reinterpret_cast<const u16x8*>(Bp);
    #pragma unroll
    for (int it = 0; it < 8; ++it)
        bl8[it * 1024 + tid] = Bp8[it * 1024 + tid];
    __syncthreads();

    // ---- ks 0..7: A from mi/mt (bf16) ----
    #pragma unroll
    for (int ks = 0; ks < 8; ++ks) {
        const ushort* s = (ks < 4) ? mi : mt;
        bf16x8 a0 = *reinterpret_cast<const bf16x8*>(s + (size_t)rA0 * 128 + (ks & 3) * 32 + kh);
        bf16x8 a1 = *reinterpret_cast<const bf16x8*>(s + (size_t)rA1 * 128 + (ks & 3) * 32 + kh);
        #pragma unroll
        for (int cf = 0; cf < 8; ++cf) {
            bf16x8 bb = *reinterpret_cast<const bf16x8*>(&bl8[(ks * 8 + cf) * 64 + lane]);
            acc0[cf] = __builtin_amdgcn_mfma_f32_16x16x32_bf16(a0, bb, acc0[cf], 0, 0, 0);
            acc1[cf] = __builtin_amdgcn_mfma_f32_16x16x32_bf16(a1, bb, acc1[cf], 0, 0, 0);
        }
    }
    // ---- ks 8..15: A from x_user (f32, inline cvt) ----
    const float* Xr0 = x_user + (size_t)rA0 * 256;
    const float* Xr1 = x_user + (size_t)rA1 * 256;
    #pragma unroll
    for (int ks = 8; ks < 16; ++ks) {
        int k0 = (ks - 8) * 32 + kh;
        float4 f0 = *reinterpret_cast<const float4*>(Xr0 + k0);
        float4 f1 = *reinterpret_cast<const float4*>(Xr0 + k0 + 4);
        float4 g0 = *reinterpret_cast<const float4*>(Xr1 + k0);
        float4 g1 = *reinterpret_cast<const float4*>(Xr1 + k0 + 4);
        bf16x8 a0, a1;
        a0[0] = (short)f2b(f0.x); a0[1] = (short)f2b(f0.y);
        a0[2] = (short)f2b(f0.z); a0[3] = (short)f2b(f0.w);
        a0[4] = (short)f2b(f1.x); a0[5] = (short)f2b(f1.y);
        a0[6] = (short)f2b(f1.z); a0[7] = (short)f2b(f1.w);
        a1[0] = (short)f2b(g0.x); a1[1] = (short)f2b(g0.y);
        a1[2] = (short)f2b(g0.z); a1[3] = (short)f2b(g0.w);
        a1[4] = (short)f2b(g1.x); a1[5] = (short)f2b(g1.y);
        a1[6] = (short)f2b(g1.z); a1[7] = (short)f2b(g1.w);
        #pragma unroll
        for (int cf = 0; cf < 8; ++cf) {
            bf16x8 bb = *reinterpret_cast<const bf16x8*>(&bl8[(ks * 8 + cf) * 64 + lane]);
            acc0[cf] = __builtin_amdgcn_mfma_f32_16x16x32_bf16(a0, bb, acc0[cf], 0, 0, 0);
            acc1[cf] = __builtin_amdgcn_mfma_f32_16x16x32_bf16(a1, bb, acc1[cf], 0, 0, 0);
        }
    }

    // ---- epilogue: bias + relu + store (2 row groups) ----
    const int col0 = lane & 15;
    const int rbase = blockIdx.x * 512 + wid * 32 + (lane >> 4) * 4;
    #pragma unroll
    for (int cf = 0; cf < 8; ++cf) {
        int c = cf * 16 + col0;
        float bv = bias[c];
        #pragma unroll
        for (int r = 0; r < 4; ++r) {
            int row = rbase + r;
            if (row < N) out[(size_t)row * 128 + c] = fmaxf(acc0[cf][r] + bv, 0.f);
            int row2 = rbase + 16 + r;
            if (row2 < N) out[(size_t)row2 * 128 + c] = fmaxf(acc1[cf][r] + bv, 0.f);
        }
    }
}

extern "C" void kernel_launch(void* const* d_in, const int* in_sizes, int n_in,
                              void* d_out, int out_size, void* d_ws, size_t ws_size,
                              hipStream_t stream) {
    const float* x_user  = (const float*)d_in[0];
    const float* x_image = (const float*)d_in[1];
    const float* x_text  = (const float*)d_in[2];
    const int*   edge_i  = (const int*)d_in[3];
    const int*   edge_t  = (const int*)d_in[4];
    const float* W_user  = (const float*)d_in[5];
    const float* b_user  = (const float*)d_in[6];
    const float* Wl_img  = (const float*)d_in[7];
    const float* bl_img  = (const float*)d_in[8];
    const float* Wr_img  = (const float*)d_in[9];
    const float* Wl_txt  = (const float*)d_in[10];
    const float* bl_txt  = (const float*)d_in[11];
    const float* Wr_txt  = (const float*)d_in[12];

    const int N = in_sizes[0] / 256;   // 100000 nodes per type
    const int E = in_sizes[3] / 2;     // 800000 edges per relation
    const int M = 2 * N;
    const int nblkR = (E + BK - 1) / BK;           // 196
    const int NBLK = 2 * nblkR;                    // 392 (<=512 for k_s1)
    const int nbuk = (M + 1023) >> 10;             // 196 (<=MAXBUK)

    unsigned char* xib = (unsigned char*)d_ws;         // N*128 B (fp8)
    unsigned char* xtb = xib + (size_t)N * 128;        // N*128 B (fp8)
    ushort*   mi     = (ushort*)(xtb + (size_t)N * 128); // N*128 ushort
    ushort*   mt     = mi + (size_t)N * 128;           // N*128 ushort
    ushort*   Bp     = mt + (size_t)N * 128;           // 65536
    float*    bias   = (float*)(Bp + 65536);           // 128
    int*      counts = (int*)(bias + 128);             // NBLK*nbuk
    int*      T      = counts + (size_t)NBLK * nbuk;   // 256
    int*      Bb     = T + 256;                        // nbuk+1 (pad 260)
    int*      rowptr = Bb + 260;                       // M+4
    int*      col    = rowptr + (M + 4);               // 2E
    unsigned* pairs  = (unsigned*)(col + (size_t)2 * E); // 2E u32

    const int nbP = 256;                           // pack blocks (65536 thr)
    const int nbC = (2 * N * 16 + 255) / 256;      // convert blocks (img+txt)
    k_front<<<nbP + NBLK + nbC, 256, 0, stream>>>(
        x_image, x_text, edge_i, edge_t,
        Wl_img, Wl_txt, W_user, b_user, Wr_img, Wr_txt, bl_img, bl_txt,
        xib, xtb, Bp, bias, counts, N, E, nblkR, nbuk, nbP);

    k_s1<<<nbuk, 256, 0, stream>>>(counts, T, NBLK, nbuk);
    k_s2<<<1, 256, 0, stream>>>(T, Bb, rowptr, M, 2 * E, nbuk);
    k_part1<<<NBLK, 512, 0, stream>>>(edge_i, edge_t, counts, Bb, pairs,
                                      N, E, nblkR, nbuk);
    k_part2<<<nbuk, 512, 0, stream>>>(pairs, Bb, rowptr, col, M);

    {
        dim3 g((N * 8 + 255) / 256, 2);
        k_gather_mean<<<g, 256, 0, stream>>>(xib, xtb, rowptr, col, mi, mt, N);
    }

    k_final_mfma<<<(N + 511) / 512, 1024, 131072, stream>>>(
        mi, mt, x_user, Bp, bias, (float*)d_out, N);
}

// Round 17
// 152.585 us; speedup vs baseline: 1.0408x; 1.0408x over previous
//
#include <hip/hip_runtime.h>

// ---------------------------------------------------------------------------
// HeteroGNN, round 17: r15 pipeline + occupancy-fixed final GEMM.
//   final: 1024thr/16 waves/256 rows, 1 frag-set per wave (acc[8], 32 AGPR),
//   B staged in 2x64KB LDS halves (3 barriers), grid 391 -> ~24-28 waves/CU.
//   k_s2 deleted: part1/part2 scan bucket totals T locally.
//   x_image/x_text stored fp8-e4m3 (HW cvt); means bf16; GEMM bf16 MFMA.
//   out = relu( [mean_i | mean_t | x_user] @ [Wl_i; Wl_t; W_user@(Wr_i+Wr_t)]
//               + (b_user@(Wr_i+Wr_t) + bl_i + bl_t) )        [MFMA, K=512]
// CSR: two-level bucket partition, zero global atomics (r9/r14).
// gather: 8 lanes/node, 16B(=16 fp8)/lane, unroll-4 (r15).
// MFMA 16x16x32_bf16: A row=lane&15, k=(lane>>4)*8+j; B col=lane&15;
// D col=lane&15, row=(lane>>4)*4+reg  [m89-verified].
// ---------------------------------------------------------------------------

#define BK 4096          // edges per level-1 block
#define MAXBUK 256       // >= nbuk = ceil(2N/1024) = 196

typedef __attribute__((ext_vector_type(8))) short bf16x8;
typedef __attribute__((ext_vector_type(8))) unsigned short u16x8;
typedef __attribute__((ext_vector_type(4))) float f32x4;
typedef __attribute__((ext_vector_type(2))) float f32x2;

__device__ __forceinline__ ushort f2b(float x) {
    union { float f; unsigned u; } v; v.f = x;
    unsigned r = (v.u + 0x7FFF + ((v.u >> 16) & 1)) >> 16;   // RNE
    return (ushort)r;
}
__device__ __forceinline__ float b2f(ushort u) {
    union { unsigned u; float f; } v; v.u = (unsigned)u << 16;
    return v.f;
}
// decode 4 fp8 (one u32) and accumulate into a[0..3]
__device__ __forceinline__ void acc4(unsigned w, float* a) {
    f32x2 lo = __builtin_amdgcn_cvt_pk_f32_fp8((int)w, false);
    f32x2 hi = __builtin_amdgcn_cvt_pk_f32_fp8((int)w, true);
    a[0] += lo[0]; a[1] += lo[1]; a[2] += hi[0]; a[3] += hi[1];
}

// ---- fused front: [pack | bucket hist (LDS) | fp8 convert] by block range ----
__global__ __launch_bounds__(256) void k_front(
        const float* __restrict__ x_image, const float* __restrict__ x_text,
        const int* __restrict__ edge_i, const int* __restrict__ edge_t,
        const float* __restrict__ Wl_i, const float* __restrict__ Wl_t,
        const float* __restrict__ W_user, const float* __restrict__ b_user,
        const float* __restrict__ Wr_i, const float* __restrict__ Wr_t,
        const float* __restrict__ bl_i, const float* __restrict__ bl_t,
        unsigned char* __restrict__ xib, unsigned char* __restrict__ xtb,
        ushort* __restrict__ Bp, float* __restrict__ bias,
        int* __restrict__ counts,
        int N, int E, int nblkR, int nbuk, int nbP) {
    __shared__ int h[MAXBUK];
    const int bid = blockIdx.x;
    const int tid = threadIdx.x;
    const int NBLK = 2 * nblkR;

    if (bid < nbP) {
        // ---- pack Bp [512x128] = [Wl_i; Wl_t; W_user@(Wr_i+Wr_t)] + bias ----
        int i = bid * 256 + tid;                     // < 65536
        int j = i & 7, lane = (i >> 3) & 63, cf = (i >> 9) & 7, ks = i >> 12;
        int kk = ks * 32 + (lane >> 4) * 8 + j;
        int col = cf * 16 + (lane & 15);
        float v;
        if (kk < 128)      v = Wl_i[kk * 128 + col];
        else if (kk < 256) v = Wl_t[(kk - 128) * 128 + col];
        else {
            int k2 = kk - 256;
            float s = 0.f;
            for (int c1 = 0; c1 < 128; ++c1)
                s += W_user[k2 * 128 + c1] * (Wr_i[c1 * 128 + col] + Wr_t[c1 * 128 + col]);
            v = s;
        }
        Bp[i] = f2b(v);
        if (i < 128) {
            float b = bl_i[i] + bl_t[i];
            for (int k2 = 0; k2 < 128; ++k2)
                b += b_user[k2] * (Wr_i[k2 * 128 + i] + Wr_t[k2 * 128 + i]);
            bias[i] = b;
        }
    } else if (bid < nbP + NBLK) {
        // ---- level-1 histogram of bucket = key>>10, LDS atomics only ----
        int hb = bid - nbP;
        int rel = (hb >= nblkR) ? 1 : 0;
        int blk = hb - rel * nblkR;
        const int* eg = rel ? edge_t : edge_i;
        const int relN = rel * N;
        for (int i = tid; i < nbuk; i += 256) h[i] = 0;
        __syncthreads();
        int base = blk * BK;
        #pragma unroll
        for (int j = 0; j < 4; ++j) {
            int e = base + (j * 256 + tid) * 4;
            if (e + 3 < E) {
                int4 d4 = *reinterpret_cast<const int4*>(eg + E + e);
                atomicAdd(&h[(relN + d4.x) >> 10], 1);
                atomicAdd(&h[(relN + d4.y) >> 10], 1);
                atomicAdd(&h[(relN + d4.z) >> 10], 1);
                atomicAdd(&h[(relN + d4.w) >> 10], 1);
            } else {
                for (int q = 0; q < 4; ++q) {
                    int ee = e + q;
                    if (ee < E) atomicAdd(&h[(relN + eg[E + ee]) >> 10], 1);
                }
            }
        }
        __syncthreads();
        for (int i = tid; i < nbuk; i += 256) counts[(size_t)hb * nbuk + i] = h[i];
    } else {
        // ---- x_image/x_text f32 -> fp8 e4m3 (HW cvt, RNE) ----
        int t = (bid - nbP - NBLK) * 256 + tid;
        int n8 = N * 16;
        if (t >= 2 * n8) return;
        int relc = (t >= n8) ? 1 : 0;
        const float* src = relc ? x_text : x_image;
        unsigned char* dst = relc ? xtb : xib;
        int i = relc ? t - n8 : t;
        float4 f0 = *reinterpret_cast<const float4*>(src + (size_t)i * 8);
        float4 f1 = *reinterpret_cast<const float4*>(src + (size_t)i * 8 + 4);
        int w0 = 0, w1 = 0;
        w0 = __builtin_amdgcn_cvt_pk_fp8_f32(f0.x, f0.y, w0, false);
        w0 = __builtin_amdgcn_cvt_pk_fp8_f32(f0.z, f0.w, w0, true);
        w1 = __builtin_amdgcn_cvt_pk_fp8_f32(f1.x, f1.y, w1, false);
        w1 = __builtin_amdgcn_cvt_pk_fp8_f32(f1.z, f1.w, w1, true);
        *reinterpret_cast<uint2*>(dst + (size_t)i * 8) = make_uint2((unsigned)w0, (unsigned)w1);
    }
}

// ---- s1: per-bucket exclusive prefix over blocks (in-place) + totals ----
__global__ __launch_bounds__(256) void k_s1(int* __restrict__ counts,
                                            int* __restrict__ T,
                                            int NBLK, int nbuk) {
    __shared__ int a[512];
    __shared__ int ps[256];
    const int b = blockIdx.x, t = threadIdx.x;
    a[t]       = (t < NBLK)       ? counts[(size_t)t * nbuk + b] : 0;
    a[t + 256] = (t + 256 < NBLK) ? counts[(size_t)(t + 256) * nbuk + b] : 0;
    __syncthreads();
    int x0 = a[2 * t], x1 = a[2 * t + 1];
    int s = x0 + x1;
    ps[t] = s; __syncthreads();
    for (int off = 1; off < 256; off <<= 1) {
        int add = (t >= off) ? ps[t - off] : 0;
        __syncthreads();
        ps[t] += add;
        __syncthreads();
    }
    int ex = ps[t] - s;
    if (2 * t < NBLK)     counts[(size_t)(2 * t) * nbuk + b] = ex;
    if (2 * t + 1 < NBLK) counts[(size_t)(2 * t + 1) * nbuk + b] = ex + x0;
    if (t == 255) T[b] = ps[255];
}

// ---- part1 (512 thr): local T-scan -> bases; scatter packed pairs ----
__global__ __launch_bounds__(512) void k_part1(
        const int* __restrict__ edge_i, const int* __restrict__ edge_t,
        const int* __restrict__ counts, const int* __restrict__ T,
        unsigned* __restrict__ pairs, int N, int E, int nblkR, int nbuk) {
    __shared__ int cur[MAXBUK];
    __shared__ int ps[256];
    const int bid = blockIdx.x, tid = threadIdx.x;
    // exclusive scan of T (nbuk <= 256) by threads 0..255
    int v = 0;
    if (tid < 256) { v = (tid < nbuk) ? T[tid] : 0; ps[tid] = v; }
    __syncthreads();
    for (int off = 1; off < 256; off <<= 1) {
        int add = (tid >= off && tid < 256) ? ps[tid - off] : 0;
        __syncthreads();
        if (tid < 256) ps[tid] += add;
        __syncthreads();
    }
    if (tid < nbuk)
        cur[tid] = (ps[tid] - v) + counts[(size_t)bid * nbuk + tid];
    __syncthreads();

    int rel = (bid >= nblkR) ? 1 : 0;
    int blk = bid - rel * nblkR;
    const int* eg = rel ? edge_t : edge_i;
    const int relN = rel * N;
    int base = blk * BK;
    #pragma unroll
    for (int j = 0; j < 2; ++j) {
        int e = base + (j * 512 + tid) * 4;
        if (e + 3 < E) {
            int4 d4 = *reinterpret_cast<const int4*>(eg + E + e);
            int4 s4 = *reinterpret_cast<const int4*>(eg + e);
            int k0 = relN + d4.x, k1 = relN + d4.y, k2 = relN + d4.z, k3 = relN + d4.w;
            int p0 = atomicAdd(&cur[k0 >> 10], 1);
            pairs[p0] = ((unsigned)(k0 & 1023) << 17) | (unsigned)s4.x;
            int p1 = atomicAdd(&cur[k1 >> 10], 1);
            pairs[p1] = ((unsigned)(k1 & 1023) << 17) | (unsigned)s4.y;
            int p2 = atomicAdd(&cur[k2 >> 10], 1);
            pairs[p2] = ((unsigned)(k2 & 1023) << 17) | (unsigned)s4.z;
            int p3 = atomicAdd(&cur[k3 >> 10], 1);
            pairs[p3] = ((unsigned)(k3 & 1023) << 17) | (unsigned)s4.w;
        } else {
            for (int q = 0; q < 4; ++q) {
                int ee = e + q;
                if (ee < E) {
                    int k0 = relN + eg[E + ee];
                    int p0 = atomicAdd(&cur[k0 >> 10], 1);
                    pairs[p0] = ((unsigned)(k0 & 1023) << 17) | (unsigned)eg[ee];
                }
            }
        }
    }
}

// ---- part2 (512 thr): local T-scan -> [beg,end); hist/scan -> rowptr+col ----
__global__ __launch_bounds__(512) void k_part2(
        const unsigned* __restrict__ pairs, const int* __restrict__ T,
        int* __restrict__ rowptr, int* __restrict__ col, int M, int nbuk) {
    __shared__ int h[1024];
    __shared__ int ps[512];
    __shared__ int s_beg, s_end;
    const int b = blockIdx.x, t = threadIdx.x;
    const int key0 = b << 10;
    // exclusive scan of T for this bucket's base
    int v = 0;
    if (t < 256) { v = (t < nbuk) ? T[t] : 0; ps[t] = v; }
    __syncthreads();
    for (int off = 1; off < 256; off <<= 1) {
        int add = (t >= off && t < 256) ? ps[t - off] : 0;
        __syncthreads();
        if (t < 256) ps[t] += add;
        __syncthreads();
    }
    if (t == b) { s_beg = ps[b] - v; s_end = ps[b]; }
    if (b == 0 && t == nbuk - 1) rowptr[M] = ps[nbuk - 1];   // total = 2E
    __syncthreads();
    const int beg = s_beg, end = s_end;

    h[t] = 0; h[t + 512] = 0;
    __syncthreads();
    for (int p = beg + t; p < end; p += 512)
        atomicAdd(&h[pairs[p] >> 17], 1);
    __syncthreads();
    int v0 = h[2 * t], v1 = h[2 * t + 1];
    int s = v0 + v1;
    ps[t] = s; __syncthreads();
    for (int off = 1; off < 512; off <<= 1) {
        int add = (t >= off) ? ps[t - off] : 0;
        __syncthreads();
        ps[t] += add;
        __syncthreads();
    }
    int run = ps[t] - s + beg;
    __syncthreads();
    int k = key0 + 2 * t;
    if (k < M) rowptr[k] = run;
    h[2 * t] = run; run += v0;
    if (k + 1 < M) rowptr[k + 1] = run;
    h[2 * t + 1] = run;
    __syncthreads();
    for (int p = beg + t; p < end; p += 512) {
        unsigned pr = pairs[p];
        int slot = atomicAdd(&h[pr >> 17], 1);
        col[slot] = (int)(pr & 0x1FFFFu);
    }
}

// ---- gather-mean: 8 lanes/node, 16B(16 fp8)/lane, unroll-4, bf16 means ----
__global__ __launch_bounds__(256) void k_gather_mean(
        const unsigned char* __restrict__ xib, const unsigned char* __restrict__ xtb,
        const int* __restrict__ rowptr, const int* __restrict__ col,
        ushort* __restrict__ mi, ushort* __restrict__ mt, int N) {
    int t = blockIdx.x * 256 + threadIdx.x;
    int node = t >> 3, lane = t & 7;
    if (node >= N) return;
    int rel = blockIdx.y;
    const unsigned char* xs = rel ? xtb : xib;
    ushort* mean = rel ? mt : mi;
    const int c0 = lane * 16;            // element (= byte) offset in 128-elem row
    int rb = rel * N + node;
    int beg = rowptr[rb], end = rowptr[rb + 1];
    float a[16];
    #pragma unroll
    for (int q = 0; q < 16; ++q) a[q] = 0.f;
    int j = beg;
    for (; j + 3 < end; j += 4) {
        int s0 = col[j], s1 = col[j + 1], s2 = col[j + 2], s3 = col[j + 3];
        uint4 v0 = *reinterpret_cast<const uint4*>(xs + (size_t)s0 * 128 + c0);
        uint4 v1 = *reinterpret_cast<const uint4*>(xs + (size_t)s1 * 128 + c0);
        uint4 v2 = *reinterpret_cast<const uint4*>(xs + (size_t)s2 * 128 + c0);
        uint4 v3 = *reinterpret_cast<const uint4*>(xs + (size_t)s3 * 128 + c0);
        acc4(v0.x, a + 0); acc4(v0.y, a + 4); acc4(v0.z, a + 8); acc4(v0.w, a + 12);
        acc4(v1.x, a + 0); acc4(v1.y, a + 4); acc4(v1.z, a + 8); acc4(v1.w, a + 12);
        acc4(v2.x, a + 0); acc4(v2.y, a + 4); acc4(v2.z, a + 8); acc4(v2.w, a + 12);
        acc4(v3.x, a + 0); acc4(v3.y, a + 4); acc4(v3.z, a + 8); acc4(v3.w, a + 12);
    }
    for (; j < end; ++j) {
        uint4 v0 = *reinterpret_cast<const uint4*>(xs + (size_t)col[j] * 128 + c0);
        acc4(v0.x, a + 0); acc4(v0.y, a + 4); acc4(v0.z, a + 8); acc4(v0.w, a + 12);
    }
    float r = (end > beg) ? 1.0f / (float)(end - beg) : 0.0f;
    u16x8 o0, o1;
    #pragma unroll
    for (int q = 0; q < 8; ++q) { o0[q] = f2b(a[q] * r); o1[q] = f2b(a[q + 8] * r); }
    *reinterpret_cast<u16x8*>(mean + (size_t)node * 128 + c0) = o0;
    *reinterpret_cast<u16x8*>(mean + (size_t)node * 128 + c0 + 8) = o1;
}

// ---- out = relu( [mi|mt|x_user](K=512) @ Bp + bias ) : MFMA, B in LDS ----
// 1024 thr / 16 waves / 256 rows per block; ONE frag-set per wave (acc[8]);
// B staged in 2x64KB halves; low regs -> ~24-28 waves/CU.
__global__ __launch_bounds__(1024) void k_final_mfma(
        const ushort* __restrict__ mi, const ushort* __restrict__ mt,
        const float* __restrict__ x_user, const ushort* __restrict__ Bp,
        const float* __restrict__ bias, float* __restrict__ out, int N) {
    __shared__ u16x8 bl8[4096];                  // 64 KB half of B
    const int tid = threadIdx.x;
    const int wid = tid >> 6, lane = tid & 63;   // wid 0..15
    const int r0g = blockIdx.x * 256 + wid * 16 + (lane & 15);
    const int rA0 = min(r0g, N - 1);
    const int kh = (lane >> 4) * 8;
    f32x4 acc[8] = {};

    const u16x8* Bp8 = reinterpret_cast<const u16x8*>(Bp);

    // ---- stage half 0 (ks 0..7), compute from mi/mt ----
    #pragma unroll
    for (int it = 0; it < 4; ++it)
        bl8[it * 1024 + tid] = Bp8[it * 1024 + tid];
    __syncthreads();
    #pragma unroll
    for (int ks = 0; ks < 8; ++ks) {
        const ushort* s = (ks < 4) ? mi : mt;
        bf16x8 a0 = *reinterpret_cast<const bf16x8*>(s + (size_t)rA0 * 128 + (ks & 3) * 32 + kh);
        #pragma unroll
        for (int cf = 0; cf < 8; ++cf) {
            bf16x8 bb = *reinterpret_cast<const bf16x8*>(&bl8[(ks * 8 + cf) * 64 + lane]);
            acc[cf] = __builtin_amdgcn_mfma_f32_16x16x32_bf16(a0, bb, acc[cf], 0, 0, 0);
        }
    }
    __syncthreads();                             // protect half-0 reads

    // ---- stage half 1 (ks 8..15), compute from x_user (f32, inline cvt) ----
    #pragma unroll
    for (int it = 0; it < 4; ++it)
        bl8[it * 1024 + tid] = Bp8[4096 + it * 1024 + tid];
    __syncthreads();
    const float* Xr0 = x_user + (size_t)rA0 * 256;
    #pragma unroll
    for (int ks = 0; ks < 8; ++ks) {
        int k0 = ks * 32 + kh;
        float4 f0 = *reinterpret_cast<const float4*>(Xr0 + k0);
        float4 f1 = *reinterpret_cast<const float4*>(Xr0 + k0 + 4);
        bf16x8 a0;
        a0[0] = (short)f2b(f0.x); a0[1] = (short)f2b(f0.y);
        a0[2] = (short)f2b(f0.z); a0[3] = (short)f2b(f0.w);
        a0[4] = (short)f2b(f1.x); a0[5] = (short)f2b(f1.y);
        a0[6] = (short)f2b(f1.z); a0[7] = (short)f2b(f1.w);
        #pragma unroll
        for (int cf = 0; cf < 8; ++cf) {
            bf16x8 bb = *reinterpret_cast<const bf16x8*>(&bl8[(ks * 8 + cf) * 64 + lane]);
            acc[cf] = __builtin_amdgcn_mfma_f32_16x16x32_bf16(a0, bb, acc[cf], 0, 0, 0);
        }
    }

    // ---- epilogue: bias + relu + store ----
    const int col0 = lane & 15;
    const int rbase = blockIdx.x * 256 + wid * 16 + (lane >> 4) * 4;
    #pragma unroll
    for (int cf = 0; cf < 8; ++cf) {
        int c = cf * 16 + col0;
        float bv = bias[c];
        #pragma unroll
        for (int r = 0; r < 4; ++r) {
            int row = rbase + r;
            if (row < N) out[(size_t)row * 128 + c] = fmaxf(acc[cf][r] + bv, 0.f);
        }
    }
}

extern "C" void kernel_launch(void* const* d_in, const int* in_sizes, int n_in,
                              void* d_out, int out_size, void* d_ws, size_t ws_size,
                              hipStream_t stream) {
    const float* x_user  = (const float*)d_in[0];
    const float* x_image = (const float*)d_in[1];
    const float* x_text  = (const float*)d_in[2];
    const int*   edge_i  = (const int*)d_in[3];
    const int*   edge_t  = (const int*)d_in[4];
    const float* W_user  = (const float*)d_in[5];
    const float* b_user  = (const float*)d_in[6];
    const float* Wl_img  = (const float*)d_in[7];
    const float* bl_img  = (const float*)d_in[8];
    const float* Wr_img  = (const float*)d_in[9];
    const float* Wl_txt  = (const float*)d_in[10];
    const float* bl_txt  = (const float*)d_in[11];
    const float* Wr_txt  = (const float*)d_in[12];

    const int N = in_sizes[0] / 256;   // 100000 nodes per type
    const int E = in_sizes[3] / 2;     // 800000 edges per relation
    const int M = 2 * N;
    const int nblkR = (E + BK - 1) / BK;           // 196
    const int NBLK = 2 * nblkR;                    // 392 (<=512 for k_s1)
    const int nbuk = (M + 1023) >> 10;             // 196 (<=MAXBUK)

    unsigned char* xib = (unsigned char*)d_ws;         // N*128 B (fp8)
    unsigned char* xtb = xib + (size_t)N * 128;        // N*128 B (fp8)
    ushort*   mi     = (ushort*)(xtb + (size_t)N * 128); // N*128 ushort
    ushort*   mt     = mi + (size_t)N * 128;           // N*128 ushort
    ushort*   Bp     = mt + (size_t)N * 128;           // 65536
    float*    bias   = (float*)(Bp + 65536);           // 128
    int*      counts = (int*)(bias + 128);             // NBLK*nbuk
    int*      T      = counts + (size_t)NBLK * nbuk;   // 256
    int*      rowptr = T + 256;                        // M+4
    int*      col    = rowptr + (M + 4);               // 2E
    unsigned* pairs  = (unsigned*)(col + (size_t)2 * E); // 2E u32

    const int nbP = 256;                           // pack blocks (65536 thr)
    const int nbC = (2 * N * 16 + 255) / 256;      // convert blocks (img+txt)
    k_front<<<nbP + NBLK + nbC, 256, 0, stream>>>(
        x_image, x_text, edge_i, edge_t,
        Wl_img, Wl_txt, W_user, b_user, Wr_img, Wr_txt, bl_img, bl_txt,
        xib, xtb, Bp, bias, counts, N, E, nblkR, nbuk, nbP);

    k_s1<<<nbuk, 256, 0, stream>>>(counts, T, NBLK, nbuk);
    k_part1<<<NBLK, 512, 0, stream>>>(edge_i, edge_t, counts, T, pairs,
                                      N, E, nblkR, nbuk);
    k_part2<<<nbuk, 512, 0, stream>>>(pairs, T, rowptr, col, M, nbuk);

    {
        dim3 g((N * 8 + 255) / 256, 2);
        k_gather_mean<<<g, 256, 0, stream>>>(xib, xtb, rowptr, col, mi, mt, N);
    }

    k_final_mfma<<<(N + 255) / 256, 1024, 0, stream>>>(
        mi, mt, x_user, Bp, bias, (float*)d_out, N);
}